// Round 12
// baseline (198.110 us; speedup 1.0000x reference)
//
#include <hip/hip_runtime.h>
#include <stdint.h>
#include <math.h>

#define NB 4
#define NN 4096
#define NF 256
#define ND 128
#define KVB 32
#define NR (NB * NN)
#define QKVE ((size_t)NR * ND)      // 2,097,152 elements

typedef __bf16 bf16x8 __attribute__((ext_vector_type(8)));
typedef __bf16 bf16x4v __attribute__((ext_vector_type(4)));
typedef float f32x4 __attribute__((ext_vector_type(4)));
typedef unsigned short u16x4 __attribute__((ext_vector_type(4)));

__device__ __forceinline__ unsigned short f2bf(float f) {
    union { float f; uint32_t u; } v; v.f = f;
    uint32_t r = (v.u + 0x7FFFu + ((v.u >> 16) & 1u)) >> 16;
    return (unsigned short)r;
}
__device__ __forceinline__ bf16x8 lds_read16(const unsigned short* base, int byte_off) {
    return *reinterpret_cast<const bf16x8*>(reinterpret_cast<const char*>(base) + byte_off);
}

// ------- Kernel 0+1 fused: pack adj bitmask (blocks 0..1023) + QKV proj -------
// K and V are written PRE-TILED in exact wave-contiguous fragment order:
//   KS[b][tile(128)][ms*4+ks (8)][kchunk(4)][m(16)][e(8)]   (1KB per frag block)
//   VS[b][tile(128)][ds(8)][mchunk(4)][d(16)][e(8)]         (1KB per frag block)
// so attn fragment loads are base + const + lane*16B (4-line minimum).
__global__ __launch_bounds__(256) void pack_proj(
    const int* __restrict__ adj, unsigned long long* __restrict__ pm64,
    const float* __restrict__ h,
    const float* __restrict__ Wq, const float* __restrict__ bq,
    const float* __restrict__ Wk, const float* __restrict__ bk,
    const float* __restrict__ Wv, const float* __restrict__ bv,
    unsigned short* __restrict__ qo, unsigned short* __restrict__ ks_out,
    unsigned short* __restrict__ vs, float qscale)
{
    __shared__ unsigned short h_lds[64 * 128];
    __shared__ unsigned short w_lds[128 * 128];

    const int tid = threadIdx.x;
    const int lane = tid & 63;

    if (blockIdx.x < 1024) {
        // ---------------- pack path ----------------
        const int w = tid >> 6;
        const size_t base = ((size_t)blockIdx.x * 4 + w) * 256;
        for (int o = 0; o < 32; ++o) {
            const size_t wb = base + o * 8;
            int v[8];
#pragma unroll
            for (int u = 0; u < 8; ++u)
                v[u] = adj[(wb + u) * 64 + lane];
            unsigned long long m[8];
#pragma unroll
            for (int u = 0; u < 8; ++u)
                m[u] = __ballot(v[u] != 0);
            if (lane == 0) {
#pragma unroll
                for (int u = 0; u < 8; u += 2) {
                    ulonglong2 st; st.x = m[u]; st.y = m[u + 1];
                    *reinterpret_cast<ulonglong2*>(pm64 + wb + u) = st;
                }
            }
        }
        return;
    }

    // ---------------- proj path ----------------
    const int idx = blockIdx.x - 1024;
    const int proj = idx >> 8;          // 0=Q,1=K,2=V
    const int R0 = (idx & 255) * 64;
    const int wv = tid >> 6;
    const int l15 = lane & 15;
    const int lhi = lane >> 4;

    const float* W    = proj == 0 ? Wq : (proj == 1 ? Wk : Wv);
    const float* bias = proj == 0 ? bq : (proj == 1 ? bk : bv);
    const float scale = proj == 0 ? qscale : 1.0f;

    f32x4 acc[8];
#pragma unroll
    for (int i = 0; i < 8; ++i) acc[i] = f32x4{0.f, 0.f, 0.f, 0.f};

    for (int kc = 0; kc < 2; ++kc) {
        const int c0 = kc * 128;
        __syncthreads();
#pragma unroll
        for (int p = 0; p < 8; ++p) {
            int i2 = p * 256 + tid;
            int row = i2 >> 5;
            int seg = i2 & 31;
            f32x4 hv = *reinterpret_cast<const f32x4*>(h + (size_t)(R0 + row) * NF + c0 + seg * 4);
            u16x4 hb;
            hb[0] = f2bf(hv[0]); hb[1] = f2bf(hv[1]); hb[2] = f2bf(hv[2]); hb[3] = f2bf(hv[3]);
            int byte = (row * 256 + seg * 8) ^ ((row & 7) << 4);
            *reinterpret_cast<u16x4*>(reinterpret_cast<char*>(h_lds) + byte) = hb;
        }
#pragma unroll
        for (int p = 0; p < 16; ++p) {
            int i2 = p * 256 + tid;
            int row = i2 >> 5;
            int seg = i2 & 31;
            f32x4 wv4 = *reinterpret_cast<const f32x4*>(W + (size_t)row * NF + c0 + seg * 4);
            u16x4 wb;
            wb[0] = f2bf(wv4[0]); wb[1] = f2bf(wv4[1]); wb[2] = f2bf(wv4[2]); wb[3] = f2bf(wv4[3]);
            int byte = (row * 256 + seg * 8) ^ ((row & 7) << 4);
            *reinterpret_cast<u16x4*>(reinterpret_cast<char*>(w_lds) + byte) = wb;
        }
        __syncthreads();
        const int arow = 16 * wv + l15;
#pragma unroll
        for (int ksl = 0; ksl < 4; ++ksl) {
            int k = ksl * 32 + 8 * lhi;
            bf16x8 a = lds_read16(h_lds, (arow * 256 + k * 2) ^ ((arow & 7) << 4));
#pragma unroll
            for (int cs = 0; cs < 8; ++cs) {
                int d = 16 * cs + l15;
                bf16x8 b = lds_read16(w_lds, (d * 256 + k * 2) ^ ((d & 7) << 4));
                acc[cs] = __builtin_amdgcn_mfma_f32_16x16x32_bf16(a, b, acc[cs], 0, 0, 0);
            }
        }
    }
    const int bb_ = R0 >> 12;
    const int nbase = R0 & (NN - 1);
    if (proj == 0) {
#pragma unroll
        for (int cs = 0; cs < 8; ++cs) {
            int d = 16 * cs + l15;
            float bb = bias[d];
#pragma unroll
            for (int j = 0; j < 4; ++j) {
                int row = R0 + 16 * wv + 4 * lhi + j;
                qo[(size_t)row * ND + d] = f2bf((acc[cs][j] + bb) * scale);
            }
        }
    } else if (proj == 1) {
        // K pre-tiled: idx = (b*128+pt)*4096 + (ms*4+ks)*512 + kchunk*128 + m16*8 + e
#pragma unroll
        for (int cs = 0; cs < 8; ++cs) {
            int d = 16 * cs + l15;
            float bb = bias[d];
            int ksb = d >> 5;
            int kch = (d >> 3) & 3;
            int e = d & 7;
#pragma unroll
            for (int j = 0; j < 4; ++j) {
                int row = nbase + 16 * wv + 4 * lhi + j;
                int pt = row >> 5;
                int ms = (row >> 4) & 1;
                int ml = row & 15;
                size_t oidx = ((size_t)(bb_ * 128 + pt)) * 4096
                            + (size_t)(ms * 4 + ksb) * 512 + kch * 128 + ml * 8 + e;
                ks_out[oidx] = f2bf(acc[cs][j] + bb);
            }
        }
    } else {
        // V pre-tiled: idx = (b*128+pt)*4096 + ds*512 + mchunk*128 + d16*8 + e
        const int n0 = nbase + 16 * wv + 4 * lhi;   // 4 consecutive n (e run)
        const int pt = n0 >> 5;
        const int mch = (n0 & 31) >> 3;
        const int e0 = n0 & 7;
#pragma unroll
        for (int cs = 0; cs < 8; ++cs) {
            int d = 16 * cs + l15;
            float bb = bias[d];
            u16x4 o;
#pragma unroll
            for (int j = 0; j < 4; ++j) o[j] = f2bf(acc[cs][j] + bb);
            size_t oidx = ((size_t)(bb_ * 128 + pt)) * 4096
                        + (size_t)cs * 512 + mch * 128 + l15 * 8 + e0;
            *reinterpret_cast<u16x4*>(vs + oidx) = o;
        }
    }
}

// -------- Kernel 2: barrier-free flash attention ------------------------------
// Swapped softmax (lane-local rows), log2 domain, defer-max THR=8 with
// bf16-rounded l, per-g PV interleave, K/V load rotation. K/V fragments are
// PRE-TILED so every load is base + const + lane*16B (wave-contiguous 1KB).
__global__ __launch_bounds__(256, 2) void attn(
    const unsigned short* __restrict__ Q,   // [B*N,128] bf16, scaled by 1/(sqrt(128)*ln2)
    const unsigned short* __restrict__ KS,  // tiled K (see proj)
    const unsigned short* __restrict__ VS,  // tiled V (see proj)
    const unsigned int* __restrict__ pm,    // [B*N][128] packed adj words
    float* __restrict__ out,                // split-0 partial O (and final out)
    float* __restrict__ opart1,             // splits 1.. partial O (f32)
    float* __restrict__ ml,                 // [nsplit][NR][2] (m, l) -- m in log2 units
    int ntl)                                // tiles per split (32 or 64)
{
    __shared__ unsigned short p_lds[8 * 512];  // 4 waves x 2 groups x 1KB P^T tiles

    const int tid = threadIdx.x;
    const int lane = tid & 63;
    const int w = tid >> 6;
    const int l15 = lane & 15;
    const int lhi = lane >> 4;

    const int flat = blockIdx.x;
    const int x = flat & 7;
    const int rest = flat >> 3;
    const int qt = rest & 31;
    const int s2 = rest >> 5;
    const int combo = x + 8 * s2;
    const int b = combo & 3;
    const int sp = combo >> 2;
    const int q0w = qt * 128 + w * 32;      // wave's first q row (in batch)
    const size_t bN = (size_t)b * NN;
    const int ptbase = sp * ntl;

    // per-batch tiled bases + single lane offset (elements)
    const unsigned short* Kt = KS + (size_t)b * 128 * 4096 + lane * 8;
    const unsigned short* Vt = VS + (size_t)b * 128 * 4096 + lane * 8;

    bf16x8 qf[2][4];
#pragma unroll
    for (int g = 0; g < 2; ++g)
#pragma unroll
        for (int ks = 0; ks < 4; ++ks)
            qf[g][ks] = *reinterpret_cast<const bf16x8*>(
                Q + (bN + q0w + g * 16 + l15) * ND + ks * 32 + 8 * lhi);

    const unsigned int* pmr0 = pm + (bN + (size_t)(q0w + l15)) * 128;
    const unsigned int* pmr1 = pm + (bN + (size_t)(q0w + 16 + l15)) * 128;

    f32x4 acc[2][8];
#pragma unroll
    for (int g = 0; g < 2; ++g)
#pragma unroll
        for (int i = 0; i < 8; ++i) acc[g][i] = f32x4{0.f, 0.f, 0.f, 0.f};
    float m_run[2] = {-INFINITY, -INFINITY};
    float l_part[2] = {0.f, 0.f};

    // loop-carried K/V fragments (load rotation); all loads wave-contiguous
    bf16x8 kf[2][4], vf[8];
    auto load_kf = [&](int pt) {
        const unsigned short* kb = Kt + (size_t)pt * 4096;
#pragma unroll
        for (int ms = 0; ms < 2; ++ms)
#pragma unroll
            for (int ks = 0; ks < 4; ++ks)
                kf[ms][ks] = *reinterpret_cast<const bf16x8*>(kb + (ms * 4 + ks) * 512);
    };
    auto load_vf = [&](int pt) {
        const unsigned short* vb = Vt + (size_t)pt * 4096;
#pragma unroll
        for (int ds = 0; ds < 8; ++ds)
            vf[ds] = *reinterpret_cast<const bf16x8*>(vb + ds * 512);
    };
    load_kf(ptbase);
    load_vf(ptbase);

    auto iter = [&](int ptn, unsigned int mw0, unsigned int mw1) {
        // ---- S^T = mfma(K, Q) from current kf
        f32x4 s[2][2];
#pragma unroll
        for (int g = 0; g < 2; ++g)
#pragma unroll
            for (int ms = 0; ms < 2; ++ms) s[g][ms] = f32x4{0.f, 0.f, 0.f, 0.f};
        __builtin_amdgcn_s_setprio(1);
#pragma unroll
        for (int g = 0; g < 2; ++g)
#pragma unroll
            for (int ms = 0; ms < 2; ++ms)
#pragma unroll
                for (int ks = 0; ks < 4; ++ks)
                    s[g][ms] = __builtin_amdgcn_mfma_f32_16x16x32_bf16(
                        kf[ms][ks], qf[g][ks], s[g][ms], 0, 0, 0);
        __builtin_amdgcn_s_setprio(0);

        // ---- prefetch NEXT tile's K (hides under softmax+PV)
        load_kf(ptn);

        const unsigned int mw[2] = {mw0, mw1};
        // ---- mask + local max + defer-max vote (no shfl/rescale common path)
        float smaxl[2];
        float dmax = -INFINITY;
#pragma unroll
        for (int g = 0; g < 2; ++g) {
            unsigned int mwg = mw[g] >> (4 * lhi);
#pragma unroll
            for (int ms = 0; ms < 2; ++ms)
#pragma unroll
                for (int r = 0; r < 4; ++r)
                    if (!((mwg >> (16 * ms + r)) & 1u)) s[g][ms][r] = -1.0e30f;
            float mx = fmaxf(fmaxf(fmaxf(s[g][0][0], s[g][0][1]), fmaxf(s[g][0][2], s[g][0][3])),
                             fmaxf(fmaxf(s[g][1][0], s[g][1][1]), fmaxf(s[g][1][2], s[g][1][3])));
            smaxl[g] = mx;
            dmax = fmaxf(dmax, mx - m_run[g]);
        }
        if (!__all(dmax <= 8.0f)) {        // rare after warm-up
#pragma unroll
            for (int g = 0; g < 2; ++g) {
                float mx = smaxl[g];
                mx = fmaxf(mx, __shfl_xor(mx, 16, 64));
                mx = fmaxf(mx, __shfl_xor(mx, 32, 64));
                float mnew = fmaxf(m_run[g], mx);
                float c = exp2f(m_run[g] - mnew);
                m_run[g] = mnew;
                l_part[g] *= c;
#pragma unroll
                for (int ds = 0; ds < 8; ++ds) acc[g][ds] *= c;
            }
        }

        // ---- per-g: p, P round-trip, PV (PV(g=0) overlaps softmax(g=1))
#pragma unroll
        for (int g = 0; g < 2; ++g) {
            bf16x4v pbv[2];
#pragma unroll
            for (int ms = 0; ms < 2; ++ms)
#pragma unroll
                for (int r = 0; r < 4; ++r) {
                    float p = exp2f(s[g][ms][r] - m_run[g]);   // p <= 2^8
                    __bf16 pb = (__bf16)p;
                    l_part[g] += (float)pb;    // l matches PV weights exactly
                    pbv[ms][r] = pb;
                }
            const int base = (w * 2 + g) * 1024 + l15 * 64;
#pragma unroll
            for (int ms = 0; ms < 2; ++ms)
                *reinterpret_cast<bf16x4v*>(reinterpret_cast<char*>(p_lds)
                    + base + ms * 32 + lhi * 8) = pbv[ms];
            bf16x8 pa = lds_read16(p_lds, base + lhi * 16);  // P[q=l15][m=8lhi..]
            __builtin_amdgcn_s_setprio(1);
#pragma unroll
            for (int ds = 0; ds < 8; ++ds)
                acc[g][ds] = __builtin_amdgcn_mfma_f32_16x16x32_bf16(
                    vf[ds], pa, acc[g][ds], 0, 0, 0);
            __builtin_amdgcn_s_setprio(0);
        }

        // ---- prefetch NEXT tile's V (hides under next QK^T+softmax)
        load_vf(ptn);
    };

    // mask words prefetched 4 tiles deep (uint4 per row)
    uint4 mk[2], mk2[2];
    mk[0] = *reinterpret_cast<const uint4*>(pmr0 + ptbase);
    mk[1] = *reinterpret_cast<const uint4*>(pmr1 + ptbase);
    for (int t = 0; t < ntl; t += 4) {
        int tn4 = (t + 4 < ntl) ? t + 4 : t;
        mk2[0] = *reinterpret_cast<const uint4*>(pmr0 + ptbase + tn4);
        mk2[1] = *reinterpret_cast<const uint4*>(pmr1 + ptbase + tn4);
        iter(ptbase + t + 1, mk[0].x, mk[1].x);
        iter(ptbase + t + 2, mk[0].y, mk[1].y);
        iter(ptbase + t + 3, mk[0].z, mk[1].z);
        iter(ptbase + ((t + 4 < ntl) ? t + 4 : t + 3), mk[0].w, mk[1].w);
        mk[0] = mk2[0]; mk[1] = mk2[1];
    }

    // ---- epilogue: deferred cross-lhi l reduction (2 shfls, linear=exact)
#pragma unroll
    for (int g = 0; g < 2; ++g) {
        float rs = l_part[g];
        rs += __shfl_xor(rs, 16, 64);
        rs += __shfl_xor(rs, 32, 64);
        l_part[g] = rs;
    }

    float* op = (sp == 0) ? out : (opart1 + (size_t)(sp - 1) * NR * ND);
#pragma unroll
    for (int g = 0; g < 2; ++g) {
        const size_t rowbase = (bN + q0w + g * 16 + l15) * ND;
#pragma unroll
        for (int ds = 0; ds < 8; ++ds)
            *reinterpret_cast<f32x4*>(op + rowbase + 16 * ds + 4 * lhi) = acc[g][ds];
    }
    if (lhi == 0) {
#pragma unroll
        for (int g = 0; g < 2; ++g) {
            size_t gr = bN + q0w + g * 16 + l15;
            *reinterpret_cast<float2*>(ml + ((size_t)sp * NR + gr) * 2) =
                make_float2(m_run[g], l_part[g]);
        }
    }
}

// ---------------- Kernel 3: merge the KV-splits (m is log2-domain) -------------
__global__ __launch_bounds__(256) void merge_splits(
    float* __restrict__ out, const float* __restrict__ opart1,
    const float* __restrict__ ml, int nsplit)
{
    int idx = blockIdx.x * 256 + threadIdx.x;
    int row = idx >> 5;
    int d4 = (idx & 31) * 4;
    float mmax = ml[(size_t)row * 2];
    for (int sp = 1; sp < nsplit; ++sp)
        mmax = fmaxf(mmax, ml[((size_t)sp * NR + row) * 2]);
    f32x4 o0 = *reinterpret_cast<const f32x4*>(out + (size_t)row * ND + d4);
    float w0 = exp2f(ml[(size_t)row * 2] - mmax);
    float lsum = ml[(size_t)row * 2 + 1] * w0;
    f32x4 acc;
#pragma unroll
    for (int j = 0; j < 4; ++j) acc[j] = o0[j] * w0;
    for (int sp = 1; sp < nsplit; ++sp) {
        float m_s = ml[((size_t)sp * NR + row) * 2];
        float l_s = ml[((size_t)sp * NR + row) * 2 + 1];
        float ws_ = exp2f(m_s - mmax);
        f32x4 os = *reinterpret_cast<const f32x4*>(opart1 + ((size_t)(sp - 1) * NR + row) * ND + d4);
#pragma unroll
        for (int j = 0; j < 4; ++j) acc[j] += os[j] * ws_;
        lsum += l_s * ws_;
    }
    float inv = 1.0f / lsum;
    f32x4 r;
#pragma unroll
    for (int j = 0; j < 4; ++j) r[j] = acc[j] * inv;
    *reinterpret_cast<f32x4*>(out + (size_t)row * ND + d4) = r;
}

extern "C" void kernel_launch(void* const* d_in, const int* in_sizes, int n_in,
                              void* d_out, int out_size, void* d_ws, size_t ws_size,
                              hipStream_t stream) {
    const float* h  = (const float*)d_in[0];
    const int* adj  = (const int*)d_in[1];
    const float* Wq = (const float*)d_in[2];
    const float* bq = (const float*)d_in[3];
    const float* Wk = (const float*)d_in[4];
    const float* bk = (const float*)d_in[5];
    const float* Wv = (const float*)d_in[6];
    const float* bv = (const float*)d_in[7];
    float* out = (float*)d_out;

    unsigned short* qws  = (unsigned short*)d_ws;
    unsigned short* kws  = qws + QKVE;
    unsigned short* vsws = kws + QKVE;
    float* opart1 = (float*)(vsws + QKVE);

    const size_t pm_bytes = (size_t)NB * NN * (NN / 8);          // 8.39 MB
    const size_t need4 = 3 * QKVE * 2 + 3 * QKVE * 4 + 4 * (size_t)NR * 2 * 4 + pm_bytes;
    const int nsplit = (ws_size >= need4) ? 4 : 2;
    float* mlws = opart1 + (size_t)(nsplit - 1) * NR * ND;
    unsigned int* pmws = (unsigned int*)(mlws + (size_t)nsplit * NR * 2);
    const int ntl = (NN / KVB) / nsplit;                          // 32 or 64

    // 1/(sqrt(128) * ln2): scores land in log2 units -> exp2 softmax
    const float qscale = (float)(0.08838834764831845 / 0.6931471805599453);

    pack_proj<<<dim3(1024 + 768), 256, 0, stream>>>(
        adj, (unsigned long long*)pmws,
        h, Wq, bq, Wk, bk, Wv, bv, qws, kws, vsws, qscale);
    attn<<<dim3(32 * 4 * nsplit), 256, 0, stream>>>(
        qws, kws, vsws, pmws, out, opart1, mlws, ntl);
    merge_splits<<<dim3(NR * 32 / 256), 256, 0, stream>>>(out, opart1, mlws, nsplit);
}

// Round 13
// 152.765 us; speedup vs baseline: 1.2968x; 1.2968x over previous
//
#include <hip/hip_runtime.h>
#include <stdint.h>
#include <math.h>

#define NB 4
#define NN 4096
#define NF 256
#define ND 128
#define KVB 32
#define NR (NB * NN)
#define QKVE ((size_t)NR * ND)      // 2,097,152 elements

typedef __bf16 bf16x8 __attribute__((ext_vector_type(8)));
typedef __bf16 bf16x4v __attribute__((ext_vector_type(4)));
typedef float f32x4 __attribute__((ext_vector_type(4)));
typedef unsigned short u16x4 __attribute__((ext_vector_type(4)));

__device__ __forceinline__ unsigned short f2bf(float f) {
    union { float f; uint32_t u; } v; v.f = f;
    uint32_t r = (v.u + 0x7FFFu + ((v.u >> 16) & 1u)) >> 16;
    return (unsigned short)r;
}
__device__ __forceinline__ bf16x8 lds_read16(const unsigned short* base, int byte_off) {
    return *reinterpret_cast<const bf16x8*>(reinterpret_cast<const char*>(base) + byte_off);
}
__device__ __forceinline__ void gld_lds16(const void* g, void* l) {
    __builtin_amdgcn_global_load_lds(
        (const __attribute__((address_space(1))) void*)g,
        (__attribute__((address_space(3))) void*)l, 16, 0, 0);
}

// ------- Kernel 0+1 fused: pack adj bitmask (blocks 0..1023) + QKV proj -------
// (identical to round 11 — round 12's K-pretile scatter store regressed 25us)
// V written in B-frag tile order: VS[b][tile(128)][chunk(4)][d(128)][m8]
__global__ __launch_bounds__(256) void pack_proj(
    const int* __restrict__ adj, unsigned long long* __restrict__ pm64,
    const float* __restrict__ h,
    const float* __restrict__ Wq, const float* __restrict__ bq,
    const float* __restrict__ Wk, const float* __restrict__ bk,
    const float* __restrict__ Wv, const float* __restrict__ bv,
    unsigned short* __restrict__ qo, unsigned short* __restrict__ ko,
    unsigned short* __restrict__ vs, float qscale)
{
    __shared__ unsigned short h_lds[64 * 128];
    __shared__ unsigned short w_lds[128 * 128];

    const int tid = threadIdx.x;
    const int lane = tid & 63;

    if (blockIdx.x < 1024) {
        const int w = tid >> 6;
        const size_t base = ((size_t)blockIdx.x * 4 + w) * 256;
        for (int o = 0; o < 32; ++o) {
            const size_t wb = base + o * 8;
            int v[8];
#pragma unroll
            for (int u = 0; u < 8; ++u)
                v[u] = adj[(wb + u) * 64 + lane];
            unsigned long long m[8];
#pragma unroll
            for (int u = 0; u < 8; ++u)
                m[u] = __ballot(v[u] != 0);
            if (lane == 0) {
#pragma unroll
                for (int u = 0; u < 8; u += 2) {
                    ulonglong2 st; st.x = m[u]; st.y = m[u + 1];
                    *reinterpret_cast<ulonglong2*>(pm64 + wb + u) = st;
                }
            }
        }
        return;
    }

    const int idx = blockIdx.x - 1024;
    const int proj = idx >> 8;          // 0=Q,1=K,2=V
    const int R0 = (idx & 255) * 64;
    const int wv = tid >> 6;
    const int l15 = lane & 15;
    const int lhi = lane >> 4;

    const float* W    = proj == 0 ? Wq : (proj == 1 ? Wk : Wv);
    const float* bias = proj == 0 ? bq : (proj == 1 ? bk : bv);
    const float scale = proj == 0 ? qscale : 1.0f;

    f32x4 acc[8];
#pragma unroll
    for (int i = 0; i < 8; ++i) acc[i] = f32x4{0.f, 0.f, 0.f, 0.f};

    for (int kc = 0; kc < 2; ++kc) {
        const int c0 = kc * 128;
        __syncthreads();
#pragma unroll
        for (int p = 0; p < 8; ++p) {
            int i2 = p * 256 + tid;
            int row = i2 >> 5;
            int seg = i2 & 31;
            f32x4 hv = *reinterpret_cast<const f32x4*>(h + (size_t)(R0 + row) * NF + c0 + seg * 4);
            u16x4 hb;
            hb[0] = f2bf(hv[0]); hb[1] = f2bf(hv[1]); hb[2] = f2bf(hv[2]); hb[3] = f2bf(hv[3]);
            int byte = (row * 256 + seg * 8) ^ ((row & 7) << 4);
            *reinterpret_cast<u16x4*>(reinterpret_cast<char*>(h_lds) + byte) = hb;
        }
#pragma unroll
        for (int p = 0; p < 16; ++p) {
            int i2 = p * 256 + tid;
            int row = i2 >> 5;
            int seg = i2 & 31;
            f32x4 wv4 = *reinterpret_cast<const f32x4*>(W + (size_t)row * NF + c0 + seg * 4);
            u16x4 wb;
            wb[0] = f2bf(wv4[0]); wb[1] = f2bf(wv4[1]); wb[2] = f2bf(wv4[2]); wb[3] = f2bf(wv4[3]);
            int byte = (row * 256 + seg * 8) ^ ((row & 7) << 4);
            *reinterpret_cast<u16x4*>(reinterpret_cast<char*>(w_lds) + byte) = wb;
        }
        __syncthreads();
        const int arow = 16 * wv + l15;
#pragma unroll
        for (int ks = 0; ks < 4; ++ks) {
            int k = ks * 32 + 8 * lhi;
            bf16x8 a = lds_read16(h_lds, (arow * 256 + k * 2) ^ ((arow & 7) << 4));
#pragma unroll
            for (int cs = 0; cs < 8; ++cs) {
                int d = 16 * cs + l15;
                bf16x8 b = lds_read16(w_lds, (d * 256 + k * 2) ^ ((d & 7) << 4));
                acc[cs] = __builtin_amdgcn_mfma_f32_16x16x32_bf16(a, b, acc[cs], 0, 0, 0);
            }
        }
    }
    if (proj < 2) {
        unsigned short* out = proj == 0 ? qo : ko;
#pragma unroll
        for (int cs = 0; cs < 8; ++cs) {
            int d = 16 * cs + l15;
            float bb = bias[d];
#pragma unroll
            for (int j = 0; j < 4; ++j) {
                int row = R0 + 16 * wv + 4 * lhi + j;
                out[(size_t)row * ND + d] = f2bf((acc[cs][j] + bb) * scale);
            }
        }
    } else {
        const int bb_ = R0 >> 12;
        const int nb_ = (R0 & (NN - 1)) + 16 * wv + 4 * lhi;
        const int pt = nb_ >> 5;
        const int ch = (nb_ >> 3) & 3;
        const int mm0 = nb_ & 7;
#pragma unroll
        for (int cs = 0; cs < 8; ++cs) {
            int d = 16 * cs + l15;
            float bb = bias[d];
            u16x4 o;
#pragma unroll
            for (int j = 0; j < 4; ++j) o[j] = f2bf(acc[cs][j] + bb);
            size_t oidx = ((size_t)(bb_ * 128 + pt)) * 4096 + ch * 1024 + d * 8 + mm0;
            *reinterpret_cast<u16x4*>(vs + oidx) = o;
        }
    }
}

// -------- Kernel 2: LDS-staged flash attention --------------------------------
// FIX for the L1-port bound (r10-12 nulls): K/V staged into LDS ONCE per block
// via global_load_lds (16KB/block/iter instead of 64KB through L1), waves read
// fragments via conflict-free ds_read_b128. Double-buffered, stage(t+1) before
// compute(t), one __syncthreads per tile. Softmax identical to r11 (swapped
// operands, log2 domain, defer-max THR=8, bf16-rounded l, per-g PV interleave).
__global__ __launch_bounds__(256, 2) void attn(
    const unsigned short* __restrict__ Q,   // [B*N,128] bf16, scaled 1/(sqrt(128)*ln2)
    const unsigned short* __restrict__ K,   // [B*N,128] bf16 row-major
    const unsigned short* __restrict__ VS,  // tiled V (see proj)
    const unsigned int* __restrict__ pm,    // [B*N][128] packed adj words
    float* __restrict__ out,                // split-0 partial O (and final out)
    float* __restrict__ opart1,             // splits 1.. partial O (f32)
    float* __restrict__ ml,                 // [nsplit][NR][2] (m, l) log2-domain
    int ntl)                                // tiles per split (32 or 64)
{
    __shared__ unsigned short stA[8192];   // [0..4095]=K frags, [4096..8191]=V frags
    __shared__ unsigned short stB[8192];
    __shared__ unsigned short p_lds[4096]; // 4 waves x 2 groups x 1KB P^T tiles

    const int tid = threadIdx.x;
    const int lane = tid & 63;
    const int w = tid >> 6;
    const int l15 = lane & 15;
    const int lhi = lane >> 4;

    const int flat = blockIdx.x;
    const int x = flat & 7;
    const int rest = flat >> 3;
    const int qt = rest & 31;
    const int s2 = rest >> 5;
    const int combo = x + 8 * s2;
    const int b = combo & 3;
    const int sp = combo >> 2;
    const int q0w = qt * 128 + w * 32;
    const size_t bN = (size_t)b * NN;
    const int ptbase = sp * ntl;

    const unsigned short* Kb = K + bN * ND;
    const unsigned short* Vbase = VS + (size_t)b * 128 * 4096;

    bf16x8 qf[2][4];
#pragma unroll
    for (int g = 0; g < 2; ++g)
#pragma unroll
        for (int ks = 0; ks < 4; ++ks)
            qf[g][ks] = *reinterpret_cast<const bf16x8*>(
                Q + (bN + q0w + g * 16 + l15) * ND + ks * 32 + 8 * lhi);

    const unsigned int* pmr0 = pm + (bN + (size_t)(q0w + l15)) * 128;
    const unsigned int* pmr1 = pm + (bN + (size_t)(q0w + 16 + l15)) * 128;

    f32x4 acc[2][8];
#pragma unroll
    for (int g = 0; g < 2; ++g)
#pragma unroll
        for (int i = 0; i < 8; ++i) acc[g][i] = f32x4{0.f, 0.f, 0.f, 0.f};
    float m_run[2] = {-INFINITY, -INFINITY};
    float l_part[2] = {0.f, 0.f};

    // ---- stage one KV tile (16 x 1KB chunks; 4 per wave). K chunks gather
    // the fragment image from row-major K via per-lane SOURCE addresses;
    // LDS dest is linear (rule: dest = uniform base + lane*16).
    auto stage = [&](unsigned short* st, int pt) {
        const int m0 = pt * KVB;
#pragma unroll
        for (int i = 0; i < 4; ++i) {
            int c = w * 4 + i;                  // 0..15, wave-uniform
            if (c < 8) {                        // K frag block c = ms*4+ks
                int ms = c >> 2, ks = c & 3;
                const unsigned short* src = Kb
                    + (size_t)(m0 + ms * 16 + l15) * ND + ks * 32 + lhi * 8;
                gld_lds16(src, st + c * 512);
            } else {                            // V chunk (VS tile is the LDS image)
                int vi = c - 8;
                const unsigned short* src = Vbase + (size_t)pt * 4096 + vi * 512 + lane * 8;
                gld_lds16(src, st + 4096 + vi * 512);
            }
        }
    };

    auto compute = [&](const unsigned short* st, unsigned int mw0, unsigned int mw1) {
        // kf fragments from LDS (linear 1KB chunks, conflict-free)
        bf16x8 kf[2][4];
#pragma unroll
        for (int ms = 0; ms < 2; ++ms)
#pragma unroll
            for (int ks = 0; ks < 4; ++ks)
                kf[ms][ks] = lds_read16(st, (ms * 4 + ks) * 1024 + lane * 16);

        f32x4 s[2][2];
#pragma unroll
        for (int g = 0; g < 2; ++g)
#pragma unroll
            for (int ms = 0; ms < 2; ++ms) s[g][ms] = f32x4{0.f, 0.f, 0.f, 0.f};
        __builtin_amdgcn_s_setprio(1);
#pragma unroll
        for (int g = 0; g < 2; ++g)
#pragma unroll
            for (int ms = 0; ms < 2; ++ms)
#pragma unroll
                for (int ks = 0; ks < 4; ++ks)
                    s[g][ms] = __builtin_amdgcn_mfma_f32_16x16x32_bf16(
                        kf[ms][ks], qf[g][ks], s[g][ms], 0, 0, 0);
        __builtin_amdgcn_s_setprio(0);

        // vf fragments from LDS
        bf16x8 vf[8];
#pragma unroll
        for (int ds = 0; ds < 8; ++ds)
            vf[ds] = lds_read16(st + 4096, lhi * 2048 + ds * 256 + l15 * 16);

        const unsigned int mw[2] = {mw0, mw1};
        float smaxl[2];
        float dmax = -INFINITY;
#pragma unroll
        for (int g = 0; g < 2; ++g) {
            unsigned int mwg = mw[g] >> (4 * lhi);
#pragma unroll
            for (int ms = 0; ms < 2; ++ms)
#pragma unroll
                for (int r = 0; r < 4; ++r)
                    if (!((mwg >> (16 * ms + r)) & 1u)) s[g][ms][r] = -1.0e30f;
            float mx = fmaxf(fmaxf(fmaxf(s[g][0][0], s[g][0][1]), fmaxf(s[g][0][2], s[g][0][3])),
                             fmaxf(fmaxf(s[g][1][0], s[g][1][1]), fmaxf(s[g][1][2], s[g][1][3])));
            smaxl[g] = mx;
            dmax = fmaxf(dmax, mx - m_run[g]);
        }
        if (!__all(dmax <= 8.0f)) {        // rare after warm-up
#pragma unroll
            for (int g = 0; g < 2; ++g) {
                float mx = smaxl[g];
                mx = fmaxf(mx, __shfl_xor(mx, 16, 64));
                mx = fmaxf(mx, __shfl_xor(mx, 32, 64));
                float mnew = fmaxf(m_run[g], mx);
                float c = exp2f(m_run[g] - mnew);
                m_run[g] = mnew;
                l_part[g] *= c;
#pragma unroll
                for (int ds = 0; ds < 8; ++ds) acc[g][ds] *= c;
            }
        }

#pragma unroll
        for (int g = 0; g < 2; ++g) {
            bf16x4v pbv[2];
#pragma unroll
            for (int ms = 0; ms < 2; ++ms)
#pragma unroll
                for (int r = 0; r < 4; ++r) {
                    float p = exp2f(s[g][ms][r] - m_run[g]);   // p <= 2^8
                    __bf16 pb = (__bf16)p;
                    l_part[g] += (float)pb;
                    pbv[ms][r] = pb;
                }
            const int base = (w * 2 + g) * 1024 + l15 * 64;
#pragma unroll
            for (int ms = 0; ms < 2; ++ms)
                *reinterpret_cast<bf16x4v*>(reinterpret_cast<char*>(p_lds)
                    + base + ms * 32 + lhi * 8) = pbv[ms];
            bf16x8 pa = lds_read16(p_lds, base + lhi * 16);
            __builtin_amdgcn_s_setprio(1);
#pragma unroll
            for (int ds = 0; ds < 8; ++ds)
                acc[g][ds] = __builtin_amdgcn_mfma_f32_16x16x32_bf16(
                    vf[ds], pa, acc[g][ds], 0, 0, 0);
            __builtin_amdgcn_s_setprio(0);
        }
    };

    // ---- pipeline: stage(t+1) issued before compute(t); sync per tile
    stage(stA, ptbase);
    __syncthreads();

    uint4 mk[2], mk2[2];
    mk[0] = *reinterpret_cast<const uint4*>(pmr0 + ptbase);
    mk[1] = *reinterpret_cast<const uint4*>(pmr1 + ptbase);
    for (int t = 0; t < ntl; t += 4) {
        int tn4 = (t + 4 < ntl) ? t + 4 : t;
        mk2[0] = *reinterpret_cast<const uint4*>(pmr0 + ptbase + tn4);
        mk2[1] = *reinterpret_cast<const uint4*>(pmr1 + ptbase + tn4);

        stage(stB, ptbase + t + 1);
        compute(stA, mk[0].x, mk[1].x);
        __syncthreads();
        stage(stA, ptbase + t + 2 < ptbase + ntl ? ptbase + t + 2 : ptbase + ntl - 1);
        compute(stB, mk[0].y, mk[1].y);
        __syncthreads();
        stage(stB, ptbase + t + 3 < ptbase + ntl ? ptbase + t + 3 : ptbase + ntl - 1);
        compute(stA, mk[0].z, mk[1].z);
        __syncthreads();
        stage(stA, ptbase + (t + 4 < ntl ? t + 4 : ntl - 1));
        compute(stB, mk[0].w, mk[1].w);
        __syncthreads();

        mk[0] = mk2[0]; mk[1] = mk2[1];
    }

    // ---- epilogue
#pragma unroll
    for (int g = 0; g < 2; ++g) {
        float rs = l_part[g];
        rs += __shfl_xor(rs, 16, 64);
        rs += __shfl_xor(rs, 32, 64);
        l_part[g] = rs;
    }

    float* op = (sp == 0) ? out : (opart1 + (size_t)(sp - 1) * NR * ND);
#pragma unroll
    for (int g = 0; g < 2; ++g) {
        const size_t rowbase = (bN + q0w + g * 16 + l15) * ND;
#pragma unroll
        for (int ds = 0; ds < 8; ++ds)
            *reinterpret_cast<f32x4*>(op + rowbase + 16 * ds + 4 * lhi) = acc[g][ds];
    }
    if (lhi == 0) {
#pragma unroll
        for (int g = 0; g < 2; ++g) {
            size_t gr = bN + q0w + g * 16 + l15;
            *reinterpret_cast<float2*>(ml + ((size_t)sp * NR + gr) * 2) =
                make_float2(m_run[g], l_part[g]);
        }
    }
}

// ---------------- Kernel 3: merge the KV-splits (m is log2-domain) -------------
__global__ __launch_bounds__(256) void merge_splits(
    float* __restrict__ out, const float* __restrict__ opart1,
    const float* __restrict__ ml, int nsplit)
{
    int idx = blockIdx.x * 256 + threadIdx.x;
    int row = idx >> 5;
    int d4 = (idx & 31) * 4;
    float mmax = ml[(size_t)row * 2];
    for (int sp = 1; sp < nsplit; ++sp)
        mmax = fmaxf(mmax, ml[((size_t)sp * NR + row) * 2]);
    f32x4 o0 = *reinterpret_cast<const f32x4*>(out + (size_t)row * ND + d4);
    float w0 = exp2f(ml[(size_t)row * 2] - mmax);
    float lsum = ml[(size_t)row * 2 + 1] * w0;
    f32x4 acc;
#pragma unroll
    for (int j = 0; j < 4; ++j) acc[j] = o0[j] * w0;
    for (int sp = 1; sp < nsplit; ++sp) {
        float m_s = ml[((size_t)sp * NR + row) * 2];
        float l_s = ml[((size_t)sp * NR + row) * 2 + 1];
        float ws_ = exp2f(m_s - mmax);
        f32x4 os = *reinterpret_cast<const f32x4*>(opart1 + ((size_t)(sp - 1) * NR + row) * ND + d4);
#pragma unroll
        for (int j = 0; j < 4; ++j) acc[j] += os[j] * ws_;
        lsum += l_s * ws_;
    }
    float inv = 1.0f / lsum;
    f32x4 r;
#pragma unroll
    for (int j = 0; j < 4; ++j) r[j] = acc[j] * inv;
    *reinterpret_cast<f32x4*>(out + (size_t)row * ND + d4) = r;
}

extern "C" void kernel_launch(void* const* d_in, const int* in_sizes, int n_in,
                              void* d_out, int out_size, void* d_ws, size_t ws_size,
                              hipStream_t stream) {
    const float* h  = (const float*)d_in[0];
    const int* adj  = (const int*)d_in[1];
    const float* Wq = (const float*)d_in[2];
    const float* bq = (const float*)d_in[3];
    const float* Wk = (const float*)d_in[4];
    const float* bk = (const float*)d_in[5];
    const float* Wv = (const float*)d_in[6];
    const float* bv = (const float*)d_in[7];
    float* out = (float*)d_out;

    unsigned short* qws  = (unsigned short*)d_ws;
    unsigned short* kws  = qws + QKVE;
    unsigned short* vsws = kws + QKVE;
    float* opart1 = (float*)(vsws + QKVE);

    const size_t pm_bytes = (size_t)NB * NN * (NN / 8);          // 8.39 MB
    const size_t need4 = 3 * QKVE * 2 + 3 * QKVE * 4 + 4 * (size_t)NR * 2 * 4 + pm_bytes;
    const int nsplit = (ws_size >= need4) ? 4 : 2;
    float* mlws = opart1 + (size_t)(nsplit - 1) * NR * ND;
    unsigned int* pmws = (unsigned int*)(mlws + (size_t)nsplit * NR * 2);
    const int ntl = (NN / KVB) / nsplit;                          // 32 or 64

    // 1/(sqrt(128) * ln2): scores land in log2 units -> exp2 softmax
    const float qscale = (float)(0.08838834764831845 / 0.6931471805599453);

    pack_proj<<<dim3(1024 + 768), 256, 0, stream>>>(
        adj, (unsigned long long*)pmws,
        h, Wq, bq, Wk, bk, Wv, bv, qws, kws, vsws, qscale);
    attn<<<dim3(32 * 4 * nsplit), 256, 0, stream>>>(
        qws, kws, vsws, pmws, out, opart1, mlws, ntl);
    merge_splits<<<dim3(NR * 32 / 256), 256, 0, stream>>>(out, opart1, mlws, nsplit);
}